// Round 1
// baseline (126.997 us; speedup 1.0000x reference)
//
#include <hip/hip_runtime.h>

#define EPS 1e-5f

typedef __attribute__((ext_vector_type(8))) __bf16 bf16x8;
typedef __attribute__((ext_vector_type(4))) float f32x4;

__device__ __forceinline__ float silu_f(float v) {
  return v / (1.f + __expf(-v));
}

// ---------------- prep: fold BN + scales ----------------
// eff_kernel layout: [c][12] = taps 0..8, bias at 9, zero pad at 10,11
// (48 B stride -> every row is 16B-aligned -> 3x ds_read_b128 in fused)
__global__ __launch_bounds__(256) void prep_kernel(
    const float* __restrict__ w_experts, const float* __restrict__ bn_gamma,
    const float* __restrict__ bn_beta, const float* __restrict__ bn_mean,
    const float* __restrict__ bn_var, const float* __restrict__ scales,
    const float* __restrict__ w_out, const float* __restrict__ out_gamma,
    const float* __restrict__ out_beta, const float* __restrict__ out_mean,
    const float* __restrict__ out_var,
    float* __restrict__ eff_kernel, __bf16* __restrict__ w_eff,
    float* __restrict__ bias2)
{
  const int t = threadIdx.x;
  if (blockIdx.x == 0) {
    const int c = t;
    float k9[9];
#pragma unroll
    for (int r = 0; r < 9; ++r) k9[r] = 0.f;
    float bias = 0.f;
    for (int e = 0; e < 9; ++e) {
      const int ec = e * 256 + c;
      const float tt = bn_gamma[ec] * rsqrtf(bn_var[ec] + EPS);
      const float sc = scales[ec];
      const float es = tt * sc;
      bias += (bn_beta[ec] - bn_mean[ec] * tt) * sc;
      const float* wp = w_experts + (size_t)ec * 9;
#pragma unroll
      for (int r = 0; r < 9; ++r) k9[r] += es * wp[r];
    }
#pragma unroll
    for (int r = 0; r < 9; ++r) eff_kernel[c * 12 + r] = k9[r];
    eff_kernel[c * 12 + 9]  = bias;
    eff_kernel[c * 12 + 10] = 0.f;
    eff_kernel[c * 12 + 11] = 0.f;
    const float t2 = out_gamma[c] * rsqrtf(out_var[c] + EPS);
    bias2[c] = out_beta[c] - out_mean[c] * t2;
  } else {
    const int i = (blockIdx.x - 1) * 256 + t;   // 0..65535
    const int o = i >> 8;
    const float t2 = out_gamma[o] * rsqrtf(out_var[o] + EPS);
    w_eff[i] = (__bf16)(w_out[i] * t2);
  }
}

// ---------------- fused: depthwise 3x3 + SiLU -> LDS -> MFMA out-proj -------
// 256 blocks x 1024 threads (16 waves = 4/SIMD, 1 block/CU).
// Block owns TWO image rows (h0, h0+1): loads 4 x-rows for 2 output rows
// (2x halo traffic instead of 3x). id&7 = batch -> each XCD runs exactly its
// batch's 32 blocks on its 32 CUs (x[b]=4.19MB ~ fits 4MiB L2).
// Phases: dw(ch 0..127) | barrier | GEMM kk0..3 (reads ch<128) interleaved
// with dw(ch 128..255) (writes ch>=128, disjoint) | barrier | GEMM kk4..7.
__global__ __launch_bounds__(1024, 4) void fused_kernel(
    const float* __restrict__ x, const float* __restrict__ eff_kernel,
    const __bf16* __restrict__ w_eff, const float* __restrict__ bias2,
    float* __restrict__ out)
{
  __shared__ __align__(16) __bf16 B_lds[128 * 264];   // [2 rows * 64 px][ch]
  __shared__ __align__(16) float kern_s[256 * 12];

  const int t = threadIdx.x;
  const int id = blockIdx.x;
  const int b = id & 7;           // XCD-local batch
  const int h0 = (id >> 3) * 2;   // 0,2,..,62

  for (int i = t; i < 3072; i += 1024) kern_s[i] = eff_kernel[i];

  const int lane = t & 63;
  const int wv = t >> 6;        // 0..15
  const int lg = lane >> 4;     // 0..3
  const int wq = lane & 15;     // 0..15
  const int w4 = wq * 4;
  const bool up_ok = (h0 > 0), dn_ok = (h0 < 62);
  const float4 z4 = make_float4(0.f, 0.f, 0.f, 0.f);

  auto dw_loads = [&](int it, float4* v) {
    const int ch = it * 64 + wv * 4 + lg;
    const float* xc = x + (size_t)(b * 256 + ch) * 4096 + w4;
    v[1] = *(const float4*)(xc + h0 * 64);
    v[2] = *(const float4*)(xc + (h0 + 1) * 64);
    v[0] = up_ok ? *(const float4*)(xc + (h0 - 1) * 64) : z4;
    v[3] = dn_ok ? *(const float4*)(xc + (h0 + 2) * 64) : z4;
  };

  auto dw_compute = [&](int it, const float4* v) {
    const int ch = it * 64 + wv * 4 + lg;
    const f32x4* kp = (const f32x4*)(kern_s + ch * 12);
    const f32x4 ka = kp[0], kb = kp[1], kc = kp[2];
    float rowv[4][6];
#pragma unroll
    for (int r = 0; r < 4; ++r) {
      const float vl = __shfl_up(v[r].w, 1);
      const float vr = __shfl_down(v[r].x, 1);
      rowv[r][0] = (wq == 0) ? 0.f : vl;    // SAME left edge
      rowv[r][1] = v[r].x; rowv[r][2] = v[r].y;
      rowv[r][3] = v[r].z; rowv[r][4] = v[r].w;
      rowv[r][5] = (wq == 15) ? 0.f : vr;   // SAME right edge
    }
    const float k0 = ka[0], k1 = ka[1], k2 = ka[2];
    const float k3 = ka[3], k4 = kb[0], k5 = kb[1];
    const float k6 = kb[2], k7 = kb[3], k8 = kc[0];
    const float bias = kc[1];
#pragma unroll
    for (int rr = 0; rr < 2; ++rr) {        // two output rows share loads
#pragma unroll
      for (int j = 0; j < 4; ++j) {
        float s = bias
          + k0 * rowv[rr][j]     + k1 * rowv[rr][j + 1]     + k2 * rowv[rr][j + 2]
          + k3 * rowv[rr + 1][j] + k4 * rowv[rr + 1][j + 1] + k5 * rowv[rr + 1][j + 2]
          + k6 * rowv[rr + 2][j] + k7 * rowv[rr + 2][j + 1] + k8 * rowv[rr + 2][j + 2];
        B_lds[(rr * 64 + w4 + j) * 264 + ch] = (__bf16)silu_f(s);
      }
    }
  };

  // ---- GEMM config: per wave 32(o) x 64(p) on one of the 2 rows
  const int wrow   = wv >> 3;        // which image row
  const int wave_o = (wv & 7) * 32;
  const int quad = lg, l15 = wq;

  f32x4 acc[2][4];
#pragma unroll
  for (int i = 0; i < 2; ++i)
#pragma unroll
    for (int j = 0; j < 4; ++j) acc[i][j] = (f32x4){0.f, 0.f, 0.f, 0.f};

  auto gemm_step = [&](int kk) {
    bf16x8 af[2], bv[4];
#pragma unroll
    for (int i = 0; i < 2; ++i)
      af[i] = *(const bf16x8*)&w_eff[(size_t)(wave_o + i * 16 + l15) * 256 + kk * 32 + quad * 8];
#pragma unroll
    for (int j = 0; j < 4; ++j)
      bv[j] = *(const bf16x8*)&B_lds[(wrow * 64 + j * 16 + l15) * 264 + kk * 32 + quad * 8];
#pragma unroll
    for (int i = 0; i < 2; ++i)
#pragma unroll
      for (int j = 0; j < 4; ++j)
        acc[i][j] = __builtin_amdgcn_mfma_f32_16x16x32_bf16(af[i], bv[j], acc[i][j], 0, 0, 0);
  };

  float4 va[4], vb[4];
  dw_loads(0, va); dw_loads(1, vb);   // issue before barrier: overlap staging
  __syncthreads();                    // kern_s ready
  dw_compute(0, va); dw_compute(1, vb);
  __syncthreads();                    // B_lds ch 0..127 ready
  // phase B: GEMM over ch<128 interleaved with depthwise ch>=128
  dw_loads(2, va);                    // HBM latency hides under kk0/kk1 MFMA
  gemm_step(0); gemm_step(1);
  dw_compute(2, va);
  dw_loads(3, vb);                    // hides under kk2/kk3
  gemm_step(2); gemm_step(3);
  dw_compute(3, vb);
  __syncthreads();                    // B_lds ch 128..255 ready
  gemm_step(4); gemm_step(5); gemm_step(6); gemm_step(7);

  // epilogue: bias + SiLU, fp32 NCHW stores
  float* outb = out + (size_t)(b * 256) * 4096 + (size_t)(h0 + wrow) * 64;
#pragma unroll
  for (int i = 0; i < 2; ++i) {
#pragma unroll
    for (int r = 0; r < 4; ++r) {
      const int o = wave_o + i * 16 + quad * 4 + r;
      const float bo = bias2[o];
#pragma unroll
      for (int j = 0; j < 4; ++j) {
        const int p = j * 16 + l15;
        outb[(size_t)o * 4096 + p] = silu_f(acc[i][j][r] + bo);
      }
    }
  }
}

extern "C" void kernel_launch(void* const* d_in, const int* in_sizes, int n_in,
                              void* d_out, int out_size, void* d_ws, size_t ws_size,
                              hipStream_t stream) {
  const float* x         = (const float*)d_in[0];
  const float* w_experts = (const float*)d_in[1];
  const float* bn_gamma  = (const float*)d_in[2];
  const float* bn_beta   = (const float*)d_in[3];
  const float* bn_mean   = (const float*)d_in[4];
  const float* bn_var    = (const float*)d_in[5];
  const float* scales    = (const float*)d_in[6];
  const float* w_out     = (const float*)d_in[7];
  const float* out_gamma = (const float*)d_in[8];
  const float* out_beta  = (const float*)d_in[9];
  const float* out_mean  = (const float*)d_in[10];
  const float* out_var   = (const float*)d_in[11];
  float* out = (float*)d_out;

  char* ws = (char*)d_ws;
  float* eff_kernel = (float*)(ws);             // 12288 B  ([256][12])
  __bf16* w_eff     = (__bf16*)(ws + 12288);    // 131072 B
  float* bias2      = (float*)(ws + 143360);    // 1 KiB

  hipLaunchKernelGGL(prep_kernel, dim3(257), dim3(256), 0, stream,
                     w_experts, bn_gamma, bn_beta, bn_mean, bn_var, scales,
                     w_out, out_gamma, out_beta, out_mean, out_var,
                     eff_kernel, w_eff, bias2);
  hipLaunchKernelGGL(fused_kernel, dim3(256), dim3(1024), 0, stream,
                     x, eff_kernel, w_eff, bias2, out);
}